// Round 1
// baseline (51060.928 us; speedup 1.0000x reference)
//
#include <hip/hip_runtime.h>
#include <math.h>

#define N_NODES 30000
#define N_EDGES 480000
#define N_GRAPH 64
#define DIN 24
#define HD 512
#define NL 6

__device__ __forceinline__ float sigmoidf_(float x) { return 1.0f / (1.0f + expf(-x)); }

// ---------------- encoder: h = x @ enc_w + enc_b  [N,24]@[24,512] ----------------
__global__ __launch_bounds__(256) void enc_kernel(const float* __restrict__ x,
                                                  const float* __restrict__ w,
                                                  const float* __restrict__ b,
                                                  float* __restrict__ h) {
    __shared__ float xs[DIN];
    int row = blockIdx.x;
    int tid = threadIdx.x;
    if (tid < DIN) xs[tid] = x[row * DIN + tid];
    __syncthreads();
    for (int c = tid; c < HD; c += 256) {
        float acc = b[c];
#pragma unroll
        for (int k = 0; k < DIN; k++) acc = fmaf(xs[k], w[k * HD + c], acc);
        h[row * HD + c] = acc;
    }
}

// ---------------- generic fp32 GEMM: C = act(A[N,512] @ W[512,512] + bias) -------
// 64x64 tile, BK=16, 256 threads, 4x4 micro-tile per thread.
template <bool RELU>
__global__ __launch_bounds__(256) void gemm512(const float* __restrict__ A,
                                               const float* __restrict__ W,
                                               const float* __restrict__ bias,
                                               float* __restrict__ C, int n) {
    __shared__ float As[16][64];
    __shared__ float Ws[16][64];
    int tid = threadIdx.x;
    int tx = tid & 15, ty = tid >> 4;
    int row0 = blockIdx.y * 64;
    int col0 = blockIdx.x * 64;
    float acc[4][4] = {};
    int lr = tid >> 2;          // 0..63 A row
    int lk = (tid & 3) * 4;     // k offset (float4)
    int wk = tid >> 4;          // 0..15 W k-row
    int wc = (tid & 15) * 4;    // W col offset

    for (int kt = 0; kt < 512; kt += 16) {
        float4 av = make_float4(0.f, 0.f, 0.f, 0.f);
        if (row0 + lr < n) av = *(const float4*)&A[(size_t)(row0 + lr) * HD + kt + lk];
        As[lk + 0][lr] = av.x; As[lk + 1][lr] = av.y;
        As[lk + 2][lr] = av.z; As[lk + 3][lr] = av.w;
        *(float4*)&Ws[wk][wc] = *(const float4*)&W[(size_t)(kt + wk) * HD + col0 + wc];
        __syncthreads();
#pragma unroll
        for (int k = 0; k < 16; k++) {
            float4 a4 = *(const float4*)&As[k][ty * 4];
            float4 b4 = *(const float4*)&Ws[k][tx * 4];
            float ar[4] = {a4.x, a4.y, a4.z, a4.w};
            float br[4] = {b4.x, b4.y, b4.z, b4.w};
#pragma unroll
            for (int i = 0; i < 4; i++)
#pragma unroll
                for (int j = 0; j < 4; j++) acc[i][j] = fmaf(ar[i], br[j], acc[i][j]);
        }
        __syncthreads();
    }
#pragma unroll
    for (int i = 0; i < 4; i++) {
        int r = row0 + ty * 4 + i;
        if (r >= n) continue;
#pragma unroll
        for (int j = 0; j < 4; j++) {
            int c = col0 + tx * 4 + j;
            float v = acc[i][j] + bias[c];
            if (RELU) v = fmaxf(v, 0.0f);
            C[(size_t)r * HD + c] = v;
        }
    }
}

// ---------------- fused GRU: h_new = GRU(m, h) with gi=m@wih, gh=h@whh -----------
// 64 rows x 32 cols tile; six K=512 accumulations per tile; gates in-register.
__global__ __launch_bounds__(256) void gru_kernel(const float* __restrict__ M,
                                                  const float* __restrict__ Hc,
                                                  const float* __restrict__ wih,
                                                  const float* __restrict__ whh,
                                                  const float* __restrict__ bih,
                                                  const float* __restrict__ bhh,
                                                  float* __restrict__ Hn, int n) {
    __shared__ float Ms[16][64];
    __shared__ float Hs[16][64];
    __shared__ float Wi[3][16][32];
    __shared__ float Wh[3][16][32];
    int tid = threadIdx.x;
    int tx = tid & 15, ty = tid >> 4;
    int row0 = blockIdx.y * 64;
    int col0 = blockIdx.x * 32;
    float gi[3][4][2] = {};
    float gh[3][4][2] = {};
    int lr = tid >> 2;
    int lk = (tid & 3) * 4;

    for (int kt = 0; kt < 512; kt += 16) {
        float4 mv = make_float4(0.f, 0.f, 0.f, 0.f);
        float4 hv = make_float4(0.f, 0.f, 0.f, 0.f);
        if (row0 + lr < n) {
            mv = *(const float4*)&M[(size_t)(row0 + lr) * HD + kt + lk];
            hv = *(const float4*)&Hc[(size_t)(row0 + lr) * HD + kt + lk];
        }
        Ms[lk + 0][lr] = mv.x; Ms[lk + 1][lr] = mv.y;
        Ms[lk + 2][lr] = mv.z; Ms[lk + 3][lr] = mv.w;
        Hs[lk + 0][lr] = hv.x; Hs[lk + 1][lr] = hv.y;
        Hs[lk + 2][lr] = hv.z; Hs[lk + 3][lr] = hv.w;
        for (int idx = tid; idx < 384; idx += 256) {
            int g = idx >> 7;
            int rem = idx & 127;
            int k = rem >> 3;
            int c4 = (rem & 7) * 4;
            *(float4*)&Wi[g][k][c4] =
                *(const float4*)&wih[(size_t)(kt + k) * (3 * HD) + g * HD + col0 + c4];
            *(float4*)&Wh[g][k][c4] =
                *(const float4*)&whh[(size_t)(kt + k) * (3 * HD) + g * HD + col0 + c4];
        }
        __syncthreads();
#pragma unroll
        for (int k = 0; k < 16; k++) {
            float4 am = *(const float4*)&Ms[k][ty * 4];
            float4 ah = *(const float4*)&Hs[k][ty * 4];
            float amr[4] = {am.x, am.y, am.z, am.w};
            float ahr[4] = {ah.x, ah.y, ah.z, ah.w};
#pragma unroll
            for (int g = 0; g < 3; g++) {
                float2 bi = *(const float2*)&Wi[g][k][tx * 2];
                float2 bh = *(const float2*)&Wh[g][k][tx * 2];
                float bir[2] = {bi.x, bi.y};
                float bhr[2] = {bh.x, bh.y};
#pragma unroll
                for (int i = 0; i < 4; i++)
#pragma unroll
                    for (int j = 0; j < 2; j++) {
                        gi[g][i][j] = fmaf(amr[i], bir[j], gi[g][i][j]);
                        gh[g][i][j] = fmaf(ahr[i], bhr[j], gh[g][i][j]);
                    }
            }
        }
        __syncthreads();
    }
#pragma unroll
    for (int i = 0; i < 4; i++) {
        int r = row0 + ty * 4 + i;
        if (r >= n) continue;
#pragma unroll
        for (int j = 0; j < 2; j++) {
            int c = col0 + tx * 2 + j;
            float xr = gi[0][i][j] + bih[c] + gh[0][i][j] + bhh[c];
            float xz = gi[1][i][j] + bih[HD + c] + gh[1][i][j] + bhh[HD + c];
            float rg = sigmoidf_(xr);
            float zg = sigmoidf_(xz);
            float ng = tanhf(gi[2][i][j] + bih[2 * HD + c] + rg * (gh[2][i][j] + bhh[2 * HD + c]));
            float hold = Hc[(size_t)r * HD + c];
            Hn[(size_t)r * HD + c] = (1.0f - zg) * ng + zg * hold;
        }
    }
}

// ---------------- aggregation ----------------------------------------------------
__global__ __launch_bounds__(256) void copy4_kernel(const float4* __restrict__ src,
                                                    float4* __restrict__ dst, int n4) {
    int i = blockIdx.x * 256 + threadIdx.x;
    if (i < n4) dst[i] = src[i];
}

// one wave (64 lanes) per edge; 8 floats per lane
__global__ __launch_bounds__(256) void scatter_kernel(const float* __restrict__ msg,
                                                      float* __restrict__ m,
                                                      const int* __restrict__ src,
                                                      const int* __restrict__ dst) {
    int e = blockIdx.x * 4 + (threadIdx.x >> 6);
    int lane = threadIdx.x & 63;
    if (e >= N_EDGES) return;
    int s = src[e];
    int d = dst[e];
    const float4* mp = (const float4*)&msg[(size_t)s * HD + lane * 8];
    float4 v0 = mp[0];
    float4 v1 = mp[1];
    float* out = &m[(size_t)d * HD + lane * 8];
    atomicAdd(out + 0, v0.x); atomicAdd(out + 1, v0.y);
    atomicAdd(out + 2, v0.z); atomicAdd(out + 3, v0.w);
    atomicAdd(out + 4, v1.x); atomicAdd(out + 5, v1.y);
    atomicAdd(out + 6, v1.z); atomicAdd(out + 7, v1.w);
}

// ---------------- pooling + head --------------------------------------------------
__global__ __launch_bounds__(256) void pool_kernel(const float* __restrict__ h,
                                                   const int* __restrict__ batch,
                                                   float* __restrict__ pooled,
                                                   float* __restrict__ cnt) {
    int nrow = blockIdx.x;
    int tid = threadIdx.x;
    int b = batch[nrow];
    for (int c = tid; c < HD; c += 256) atomicAdd(&pooled[b * HD + c], h[(size_t)nrow * HD + c]);
    if (tid == 0) atomicAdd(&cnt[b], 1.0f);
}

__global__ __launch_bounds__(256) void head_kernel(const float* __restrict__ pooled,
                                                   const float* __restrict__ cnt,
                                                   const float* __restrict__ w1,
                                                   const float* __restrict__ b1,
                                                   const float* __restrict__ w2,
                                                   const float* __restrict__ b2,
                                                   float* __restrict__ out) {
    __shared__ float prow[HD];
    __shared__ float red[256];
    int g = blockIdx.x;
    int tid = threadIdx.x;
    float c = fmaxf(cnt[g], 1.0f);
    for (int j = tid; j < HD; j += 256) prow[j] = pooled[g * HD + j] / c;
    __syncthreads();
    float acc = b1[tid];
    for (int k = 0; k < HD; k++) acc = fmaf(prow[k], w1[k * 256 + tid], acc);
    red[tid] = fmaxf(acc, 0.0f) * w2[tid];
    __syncthreads();
    for (int s = 128; s > 0; s >>= 1) {
        if (tid < s) red[tid] += red[tid + s];
        __syncthreads();
    }
    if (tid == 0) out[g] = red[0] + b2[0];
}

// ---------------- launch ----------------------------------------------------------
extern "C" void kernel_launch(void* const* d_in, const int* in_sizes, int n_in,
                              void* d_out, int out_size, void* d_ws, size_t ws_size,
                              hipStream_t stream) {
    const float* x = (const float*)d_in[0];
    const int* eidx = (const int*)d_in[1];
    const int* batch = (const int*)d_in[2];
    const float* enc_w = (const float*)d_in[3];
    const float* enc_b = (const float*)d_in[4];
    const float* mlp_w1 = (const float*)d_in[5];
    const float* mlp_b1 = (const float*)d_in[6];
    const float* mlp_w2 = (const float*)d_in[7];
    const float* mlp_b2 = (const float*)d_in[8];
    const float* gru_wih = (const float*)d_in[9];
    const float* gru_whh = (const float*)d_in[10];
    const float* gru_bih = (const float*)d_in[11];
    const float* gru_bhh = (const float*)d_in[12];
    const float* head_w1 = (const float*)d_in[13];
    const float* head_b1 = (const float*)d_in[14];
    const float* head_w2 = (const float*)d_in[15];
    const float* head_b2 = (const float*)d_in[16];
    const int* src = eidx;               // edge_index[0]
    const int* dst = eidx + N_EDGES;     // edge_index[1]

    const size_t NH = (size_t)N_NODES * HD;
    float* A = (float*)d_ws;     // h
    float* B = A + NH;           // msg / h_new
    float* C = B + NH;           // hidden / m
    float* pooled = C + NH;      // [G, H]
    float* cnt = pooled + (size_t)N_GRAPH * HD;  // [G]

    enc_kernel<<<N_NODES, 256, 0, stream>>>(x, enc_w, enc_b, A);

    float* hcur = A;
    float* hoth = B;
    dim3 mgrid(8, (N_NODES + 63) / 64);   // 512/64 cols
    dim3 ggrid(16, (N_NODES + 63) / 64);  // 512/32 cols
    const int n4 = (int)(NH / 4);

    for (int l = 0; l < NL; l++) {
        const float* w1 = mlp_w1 + (size_t)l * HD * HD;
        const float* b1 = mlp_b1 + (size_t)l * HD;
        const float* w2 = mlp_w2 + (size_t)l * HD * HD;
        const float* b2 = mlp_b2 + (size_t)l * HD;
        const float* wih = gru_wih + (size_t)l * HD * 3 * HD;
        const float* whh = gru_whh + (size_t)l * HD * 3 * HD;
        const float* bih = gru_bih + (size_t)l * 3 * HD;
        const float* bhh = gru_bhh + (size_t)l * 3 * HD;

        // hidden = relu(h @ w1 + b1) -> C
        gemm512<true><<<mgrid, 256, 0, stream>>>(hcur, w1, b1, C, N_NODES);
        // msg = hidden @ w2 + b2 -> hoth
        gemm512<false><<<mgrid, 256, 0, stream>>>(C, w2, b2, hoth, N_NODES);
        // m = msg (self loop) + scatter_add(msg[src] -> dst)  -> C
        copy4_kernel<<<(n4 + 255) / 256, 256, 0, stream>>>((const float4*)hoth, (float4*)C, n4);
        scatter_kernel<<<N_EDGES / 4, 256, 0, stream>>>(hoth, C, src, dst);
        // h_new = GRU(m=C, h=hcur) -> hoth
        gru_kernel<<<ggrid, 256, 0, stream>>>(C, hcur, wih, whh, bih, bhh, hoth, N_NODES);
        float* t = hcur; hcur = hoth; hoth = t;
    }

    hipMemsetAsync(pooled, 0, ((size_t)N_GRAPH * HD + N_GRAPH) * sizeof(float), stream);
    pool_kernel<<<N_NODES, 256, 0, stream>>>(hcur, batch, pooled, cnt);
    head_kernel<<<N_GRAPH, 256, 0, stream>>>(pooled, cnt, head_w1, head_b1, head_w2, head_b2,
                                             (float*)d_out);
}

// Round 4
// 4025.226 us; speedup vs baseline: 12.6852x; 12.6852x over previous
//
#include <hip/hip_runtime.h>
#include <hip/hip_bf16.h>
#include <math.h>

#define N_NODES 30000
#define N_EDGES 480000
#define N_GRAPH 64
#define DIN 24
#define HD 512
#define NL 6

typedef __hip_bfloat16 bf16;
using short8 = __attribute__((ext_vector_type(8))) short;
using f32x4 = __attribute__((ext_vector_type(4))) float;

__device__ __forceinline__ float sigmoidf_(float x) { return 1.0f / (1.0f + expf(-x)); }
__device__ __forceinline__ float b2f(unsigned short u) {
    return __uint_as_float(((unsigned int)u) << 16);
}
__device__ __forceinline__ unsigned short f2b(float f) {
    bf16 b = __float2bfloat16(f);
    return *(unsigned short*)&b;
}

// ---------------- encoder: h = x @ enc_w + enc_b -> bf16 -------------------------
__global__ __launch_bounds__(256) void enc_kernel(const float* __restrict__ x,
                                                  const float* __restrict__ w,
                                                  const float* __restrict__ b,
                                                  bf16* __restrict__ h) {
    __shared__ float xs[DIN];
    int row = blockIdx.x;
    int tid = threadIdx.x;
    if (tid < DIN) xs[tid] = x[row * DIN + tid];
    __syncthreads();
    for (int c = tid; c < HD; c += 256) {
        float acc = b[c];
#pragma unroll
        for (int k = 0; k < DIN; k++) acc = fmaf(xs[k], w[k * HD + c], acc);
        h[(size_t)row * HD + c] = __float2bfloat16(acc);
    }
}

// ---------------- weight transpose + hi/lo split: W[l][K][Nc] f32 -> Wt{H,L}[l][Nc][K]
__global__ __launch_bounds__(256) void twcvt_kernel(const float* __restrict__ W,
                                                    bf16* __restrict__ WtH,
                                                    bf16* __restrict__ WtL, int Nc) {
    __shared__ float s[32][33];
    int l = blockIdx.z;
    const float* Wp = W + (size_t)l * HD * Nc;
    size_t ob = (size_t)l * HD * Nc;
    int k0 = blockIdx.y * 32, c0 = blockIdx.x * 32;
    int tx = threadIdx.x & 31, ty = threadIdx.x >> 5;
    for (int r = ty; r < 32; r += 8) s[r][tx] = Wp[(size_t)(k0 + r) * Nc + c0 + tx];
    __syncthreads();
    for (int r = ty; r < 32; r += 8) {
        float v = s[tx][r];
        unsigned short hu = f2b(v);
        float hf = b2f(hu);
        size_t o = ob + (size_t)(c0 + r) * HD + k0 + tx;
        *(unsigned short*)&WtH[o] = hu;
        WtL[o] = __float2bfloat16(v - hf);
    }
}

// ---------------- bf16 MFMA GEMM, weight hi/lo (2 products): ---------------------
// C = act(A[n,512] @ (Whi+Wlo) + bias); tile 128x64, 4 waves, wave = 32 rows.
template <bool RELU>
__global__ __launch_bounds__(256) void gemm_mfma(const bf16* __restrict__ A,
                                                 const bf16* __restrict__ WtH,
                                                 const bf16* __restrict__ WtL,
                                                 const float* __restrict__ bias,
                                                 bf16* __restrict__ C, int n) {
    __shared__ bf16 As[128 * 32];
    __shared__ bf16 Bh[64 * 32];
    __shared__ bf16 Bl[64 * 32];
    int tid = threadIdx.x;
    int wave = tid >> 6, lane = tid & 63;
    int quad = lane >> 4, l16 = lane & 15;
    int row0 = blockIdx.y * 128, col0 = blockIdx.x * 64;
    f32x4 acc[2][4] = {};
    int sr = tid >> 2;       // 0..63
    int sk = (tid & 3) * 8;  // 8 bf16 = 16B

    for (int kt = 0; kt < 512; kt += 32) {
#pragma unroll
        for (int hh = 0; hh < 2; hh++) {
            int r = sr + hh * 64;
            float4 v = make_float4(0.f, 0.f, 0.f, 0.f);
            int grow = row0 + r;
            if (grow < n) v = *(const float4*)&A[(size_t)grow * HD + kt + sk];
            *(float4*)&As[r * 32 + sk] = v;
        }
        *(float4*)&Bh[sr * 32 + sk] = *(const float4*)&WtH[(size_t)(col0 + sr) * HD + kt + sk];
        *(float4*)&Bl[sr * 32 + sk] = *(const float4*)&WtL[(size_t)(col0 + sr) * HD + kt + sk];
        __syncthreads();
        short8 af[2];
#pragma unroll
        for (int i = 0; i < 2; i++)
            af[i] = *(const short8*)&As[(wave * 32 + i * 16 + l16) * 32 + quad * 8];
#pragma unroll
        for (int t = 0; t < 4; t++) {
            short8 bh = *(const short8*)&Bh[(t * 16 + l16) * 32 + quad * 8];
            short8 bl = *(const short8*)&Bl[(t * 16 + l16) * 32 + quad * 8];
#pragma unroll
            for (int i = 0; i < 2; i++) {
                acc[i][t] = __builtin_amdgcn_mfma_f32_16x16x32_bf16(af[i], bh, acc[i][t], 0, 0, 0);
                acc[i][t] = __builtin_amdgcn_mfma_f32_16x16x32_bf16(af[i], bl, acc[i][t], 0, 0, 0);
            }
        }
        __syncthreads();
    }
#pragma unroll
    for (int t = 0; t < 4; t++) {
        int col = col0 + t * 16 + l16;
        float bb = bias[col];
#pragma unroll
        for (int i = 0; i < 2; i++) {
#pragma unroll
            for (int r = 0; r < 4; r++) {
                int row = row0 + wave * 32 + i * 16 + quad * 4 + r;
                if (row < n) {
                    float v = acc[i][t][r] + bb;
                    if (RELU) v = fmaxf(v, 0.0f);
                    C[(size_t)row * HD + col] = __float2bfloat16(v);
                }
            }
        }
    }
}

// ---------------- fused GRU (MFMA, weight hi/lo): tile 64x64, wave = 16 rows -----
__global__ __launch_bounds__(256) void gru_mfma(const bf16* __restrict__ M,
                                                const bf16* __restrict__ Hc,
                                                const bf16* __restrict__ WiH,
                                                const bf16* __restrict__ WiL,
                                                const bf16* __restrict__ WhH,
                                                const bf16* __restrict__ WhL,
                                                const float* __restrict__ bih,
                                                const float* __restrict__ bhh,
                                                bf16* __restrict__ Hn, int n) {
    __shared__ bf16 Ms[64 * 32];
    __shared__ bf16 Hs[64 * 32];
    __shared__ bf16 Ws[12][64 * 32];  // [gate*2 + (0=ih,...)]: 0..5 = Wi g{hi,lo}, 6..11 = Wh
    int tid = threadIdx.x;
    int wave = tid >> 6, lane = tid & 63;
    int quad = lane >> 4, l16 = lane & 15;
    int row0 = blockIdx.y * 64, col0 = blockIdx.x * 64;
    f32x4 acc[6][4] = {};  // [0..2]=gi r,z,n  [3..5]=gh r,z,n
    int sr = tid >> 2;
    int sk = (tid & 3) * 8;

    for (int kt = 0; kt < 512; kt += 32) {
        {
            float4 mv = make_float4(0.f, 0.f, 0.f, 0.f);
            float4 hv = mv;
            int grow = row0 + sr;
            if (grow < n) {
                mv = *(const float4*)&M[(size_t)grow * HD + kt + sk];
                hv = *(const float4*)&Hc[(size_t)grow * HD + kt + sk];
            }
            *(float4*)&Ms[sr * 32 + sk] = mv;
            *(float4*)&Hs[sr * 32 + sk] = hv;
        }
#pragma unroll
        for (int g = 0; g < 3; g++) {
            size_t wo = (size_t)(g * HD + col0 + sr) * HD + kt + sk;
            *(float4*)&Ws[g * 2 + 0][sr * 32 + sk] = *(const float4*)&WiH[wo];
            *(float4*)&Ws[g * 2 + 1][sr * 32 + sk] = *(const float4*)&WiL[wo];
            *(float4*)&Ws[6 + g * 2 + 0][sr * 32 + sk] = *(const float4*)&WhH[wo];
            *(float4*)&Ws[6 + g * 2 + 1][sr * 32 + sk] = *(const float4*)&WhL[wo];
        }
        __syncthreads();
        short8 am = *(const short8*)&Ms[(wave * 16 + l16) * 32 + quad * 8];
        short8 ah = *(const short8*)&Hs[(wave * 16 + l16) * 32 + quad * 8];
#pragma unroll
        for (int t = 0; t < 4; t++) {
            int fo = (t * 16 + l16) * 32 + quad * 8;
#pragma unroll
            for (int g = 0; g < 3; g++) {
                short8 b0 = *(const short8*)&Ws[g * 2 + 0][fo];
                short8 b1 = *(const short8*)&Ws[g * 2 + 1][fo];
                acc[g][t] = __builtin_amdgcn_mfma_f32_16x16x32_bf16(am, b0, acc[g][t], 0, 0, 0);
                acc[g][t] = __builtin_amdgcn_mfma_f32_16x16x32_bf16(am, b1, acc[g][t], 0, 0, 0);
                short8 c0 = *(const short8*)&Ws[6 + g * 2 + 0][fo];
                short8 c1 = *(const short8*)&Ws[6 + g * 2 + 1][fo];
                acc[3 + g][t] = __builtin_amdgcn_mfma_f32_16x16x32_bf16(ah, c0, acc[3 + g][t], 0, 0, 0);
                acc[3 + g][t] = __builtin_amdgcn_mfma_f32_16x16x32_bf16(ah, c1, acc[3 + g][t], 0, 0, 0);
            }
        }
        __syncthreads();
    }
    const unsigned short* hp = (const unsigned short*)Hc;
#pragma unroll
    for (int t = 0; t < 4; t++) {
        int col = col0 + t * 16 + l16;
        float bir = bih[col], biz = bih[HD + col], bin = bih[2 * HD + col];
        float bhr = bhh[col], bhz = bhh[HD + col], bhn = bhh[2 * HD + col];
#pragma unroll
        for (int r = 0; r < 4; r++) {
            int row = row0 + wave * 16 + quad * 4 + r;
            if (row < n) {
                float xr = acc[0][t][r] + bir + acc[3][t][r] + bhr;
                float xz = acc[1][t][r] + biz + acc[4][t][r] + bhz;
                float rg = sigmoidf_(xr);
                float zg = sigmoidf_(xz);
                float ng = tanhf(acc[2][t][r] + bin + rg * (acc[5][t][r] + bhn));
                float hold = b2f(hp[(size_t)row * HD + col]);
                Hn[(size_t)row * HD + col] = __float2bfloat16((1.0f - zg) * ng + zg * hold);
            }
        }
    }
}

// ---------------- CSR build (elist u16; deg reused as cursor) --------------------
__global__ __launch_bounds__(256) void deg_kernel(const int* __restrict__ dst,
                                                  int* __restrict__ deg) {
    int e = blockIdx.x * 256 + threadIdx.x;
    if (e < N_EDGES) atomicAdd(&deg[dst[e]], 1);
}

__global__ __launch_bounds__(1024) void scan_kernel(const int* __restrict__ deg,
                                                    int* __restrict__ offs) {
    __shared__ int buf[1024];
    __shared__ int carry_s;
    int tid = threadIdx.x;
    if (tid == 0) carry_s = 0;
    __syncthreads();
    for (int base = 0; base < N_NODES; base += 1024) {
        int v = (base + tid < N_NODES) ? deg[base + tid] : 0;
        buf[tid] = v;
        __syncthreads();
        for (int s = 1; s < 1024; s <<= 1) {
            int t = (tid >= s) ? buf[tid - s] : 0;
            __syncthreads();
            buf[tid] += t;
            __syncthreads();
        }
        int incl = buf[tid];
        if (base + tid < N_NODES) offs[base + tid] = carry_s + incl - v;
        __syncthreads();
        if (tid == 0) carry_s += buf[1023];
        __syncthreads();
    }
    if (tid == 0) offs[N_NODES] = carry_s;
}

__global__ __launch_bounds__(256) void bucket_kernel(const int* __restrict__ src,
                                                     const int* __restrict__ dst,
                                                     const int* __restrict__ offs,
                                                     int* __restrict__ cursor,
                                                     unsigned short* __restrict__ elist) {
    int e = blockIdx.x * 256 + threadIdx.x;
    if (e >= N_EDGES) return;
    int d = dst[e];
    int pos = atomicAdd(&cursor[d], 1);
    elist[offs[d] + pos] = (unsigned short)src[e];
}

// ---------------- gather-sum: m[n] = msg[n] + sum in-edges (fp32 acc) ------------
__global__ __launch_bounds__(256) void gather_kernel(const bf16* __restrict__ msg,
                                                     bf16* __restrict__ m,
                                                     const unsigned short* __restrict__ elist,
                                                     const int* __restrict__ offs) {
    int nid = blockIdx.x, tid = threadIdx.x;
    int beg = offs[nid], end = offs[nid + 1];
    const unsigned int* mp = (const unsigned int*)msg;  // 2 bf16 per uint
    unsigned int u = mp[(size_t)nid * 256 + tid];
    float ax = b2f((unsigned short)(u & 0xffffu));
    float ay = b2f((unsigned short)(u >> 16));
    int e = beg;
    for (; e + 1 < end; e += 2) {
        unsigned int v0 = mp[(size_t)elist[e] * 256 + tid];
        unsigned int v1 = mp[(size_t)elist[e + 1] * 256 + tid];
        ax += b2f((unsigned short)(v0 & 0xffffu)) + b2f((unsigned short)(v1 & 0xffffu));
        ay += b2f((unsigned short)(v0 >> 16)) + b2f((unsigned short)(v1 >> 16));
    }
    if (e < end) {
        unsigned int v0 = mp[(size_t)elist[e] * 256 + tid];
        ax += b2f((unsigned short)(v0 & 0xffffu));
        ay += b2f((unsigned short)(v0 >> 16));
    }
    unsigned int out = ((unsigned int)f2b(ay) << 16) | (unsigned int)f2b(ax);
    ((unsigned int*)m)[(size_t)nid * 256 + tid] = out;
}

// ---------------- pooling + head -------------------------------------------------
__global__ __launch_bounds__(256) void pool_kernel(const bf16* __restrict__ h,
                                                   const int* __restrict__ batch,
                                                   float* __restrict__ pooled,
                                                   float* __restrict__ cnt) {
    int nrow = blockIdx.x, tid = threadIdx.x;
    int b = batch[nrow];
    const unsigned short* hp = (const unsigned short*)h;
    for (int c = tid; c < HD; c += 256)
        atomicAdd(&pooled[b * HD + c], b2f(hp[(size_t)nrow * HD + c]));
    if (tid == 0) atomicAdd(&cnt[b], 1.0f);
}

__global__ __launch_bounds__(256) void head_kernel(const float* __restrict__ pooled,
                                                   const float* __restrict__ cnt,
                                                   const float* __restrict__ w1,
                                                   const float* __restrict__ b1,
                                                   const float* __restrict__ w2,
                                                   const float* __restrict__ b2,
                                                   float* __restrict__ out) {
    __shared__ float prow[HD];
    __shared__ float red[256];
    int g = blockIdx.x, tid = threadIdx.x;
    float c = fmaxf(cnt[g], 1.0f);
    for (int j = tid; j < HD; j += 256) prow[j] = pooled[g * HD + j] / c;
    __syncthreads();
    float acc = b1[tid];
    for (int k = 0; k < HD; k++) acc = fmaf(prow[k], w1[k * 256 + tid], acc);
    red[tid] = fmaxf(acc, 0.0f) * w2[tid];
    __syncthreads();
    for (int s = 128; s > 0; s >>= 1) {
        if (tid < s) red[tid] += red[tid + s];
        __syncthreads();
    }
    if (tid == 0) out[g] = red[0] + b2[0];
}

// ---------------- launch ---------------------------------------------------------
extern "C" void kernel_launch(void* const* d_in, const int* in_sizes, int n_in,
                              void* d_out, int out_size, void* d_ws, size_t ws_size,
                              hipStream_t stream) {
    const float* x = (const float*)d_in[0];
    const int* eidx = (const int*)d_in[1];
    const int* batch = (const int*)d_in[2];
    const float* enc_w = (const float*)d_in[3];
    const float* enc_b = (const float*)d_in[4];
    const float* mlp_w1 = (const float*)d_in[5];
    const float* mlp_b1 = (const float*)d_in[6];
    const float* mlp_w2 = (const float*)d_in[7];
    const float* mlp_b2 = (const float*)d_in[8];
    const float* gru_wih = (const float*)d_in[9];
    const float* gru_whh = (const float*)d_in[10];
    const float* gru_bih = (const float*)d_in[11];
    const float* gru_bhh = (const float*)d_in[12];
    const float* head_w1 = (const float*)d_in[13];
    const float* head_b1 = (const float*)d_in[14];
    const float* head_w2 = (const float*)d_in[15];
    const float* head_b2 = (const float*)d_in[16];
    const int* src = eidx;
    const int* dst = eidx + N_EDGES;

    const size_t NH = (size_t)N_NODES * HD;
    char* p = (char*)d_ws;
    auto alloc = [&](size_t bytes) { char* q = p; p += (bytes + 255) & ~(size_t)255; return q; };
    bf16* S0 = (bf16*)alloc(NH * 2);  // h (initial) / rotating
    bf16* S1 = (bf16*)alloc(NH * 2);
    bf16* S2 = (bf16*)alloc(NH * 2);  // msg buffer
    bf16* w1tH = (bf16*)alloc((size_t)NL * HD * HD * 2);
    bf16* w1tL = (bf16*)alloc((size_t)NL * HD * HD * 2);
    bf16* w2tH = (bf16*)alloc((size_t)NL * HD * HD * 2);
    bf16* w2tL = (bf16*)alloc((size_t)NL * HD * HD * 2);
    bf16* wihtH = (bf16*)alloc((size_t)NL * 3 * HD * HD * 2);
    bf16* wihtL = (bf16*)alloc((size_t)NL * 3 * HD * HD * 2);
    bf16* whhtH = (bf16*)alloc((size_t)NL * 3 * HD * HD * 2);
    bf16* whhtL = (bf16*)alloc((size_t)NL * 3 * HD * HD * 2);
    float* pooled = (float*)alloc((size_t)N_GRAPH * HD * 4);
    float* cnt = (float*)alloc(N_GRAPH * 4);
    int* deg = (int*)alloc((N_NODES + 1) * 4);   // also cursor
    int* offs = (int*)alloc((N_NODES + 1) * 4);
    unsigned short* elist = (unsigned short*)alloc((size_t)N_EDGES * 2);
    // total ~144 MB (< 150.5 MB proven safe in R3)

    // weight transpose + hi/lo split
    twcvt_kernel<<<dim3(16, 16, NL), 256, 0, stream>>>(mlp_w1, w1tH, w1tL, HD);
    twcvt_kernel<<<dim3(16, 16, NL), 256, 0, stream>>>(mlp_w2, w2tH, w2tL, HD);
    twcvt_kernel<<<dim3(48, 16, NL), 256, 0, stream>>>(gru_wih, wihtH, wihtL, 3 * HD);
    twcvt_kernel<<<dim3(48, 16, NL), 256, 0, stream>>>(gru_whh, whhtH, whhtL, 3 * HD);

    // CSR build
    hipMemsetAsync(deg, 0, (N_NODES + 1) * sizeof(int), stream);
    deg_kernel<<<(N_EDGES + 255) / 256, 256, 0, stream>>>(dst, deg);
    scan_kernel<<<1, 1024, 0, stream>>>(deg, offs);
    hipMemsetAsync(deg, 0, (N_NODES + 1) * sizeof(int), stream);  // reuse as cursor
    bucket_kernel<<<(N_EDGES + 255) / 256, 256, 0, stream>>>(src, dst, offs, deg, elist);

    enc_kernel<<<N_NODES, 256, 0, stream>>>(x, enc_w, enc_b, S0);

    bf16* hcur = S0;
    bf16* hoth = S1;
    dim3 ggrid(8, (N_NODES + 127) / 128);
    dim3 ugrid(8, (N_NODES + 63) / 64);

    for (int l = 0; l < NL; l++) {
        size_t wsq = (size_t)l * HD * HD;
        size_t wgq = (size_t)l * 3 * HD * HD;
        const float* b1 = mlp_b1 + (size_t)l * HD;
        const float* b2 = mlp_b2 + (size_t)l * HD;
        const float* bih = gru_bih + (size_t)l * 3 * HD;
        const float* bhh = gru_bhh + (size_t)l * 3 * HD;

        // hidden = relu(h @ w1 + b1): hcur -> hoth
        gemm_mfma<true><<<ggrid, 256, 0, stream>>>(hcur, w1tH + wsq, w1tL + wsq, b1, hoth, N_NODES);
        // msg = hidden @ w2 + b2: hoth -> S2
        gemm_mfma<false><<<ggrid, 256, 0, stream>>>(hoth, w2tH + wsq, w2tL + wsq, b2, S2, N_NODES);
        // m = msg + gather(in-edges): S2 -> hoth (hidden dead)
        gather_kernel<<<N_NODES, 256, 0, stream>>>(S2, hoth, elist, offs);
        // h_new = GRU(m=hoth, h=hcur) -> S2 (msg dead); then rotate
        gru_mfma<<<ugrid, 256, 0, stream>>>(hoth, hcur, wihtH + wgq, wihtL + wgq,
                                            whhtH + wgq, whhtL + wgq, bih, bhh, S2, N_NODES);
        // rotate: new h = S2; free buffers = old hcur, hoth
        bf16* newh = S2;
        S2 = hcur;      // old h becomes the next msg buffer
        hcur = newh;
        // hoth stays as scratch (hidden/m) next layer
    }

    hipMemsetAsync(pooled, 0, ((size_t)N_GRAPH * HD + N_GRAPH) * sizeof(float), stream);
    pool_kernel<<<N_NODES, 256, 0, stream>>>(hcur, batch, pooled, cnt);
    head_kernel<<<N_GRAPH, 256, 0, stream>>>(pooled, cnt, head_w1, head_b1, head_w2, head_b2,
                                             (float*)d_out);
}

// Round 5
// 3223.301 us; speedup vs baseline: 15.8412x; 1.2488x over previous
//
#include <hip/hip_runtime.h>
#include <hip/hip_bf16.h>
#include <math.h>

#define N_NODES 30000
#define N_EDGES 480000
#define N_GRAPH 64
#define DIN 24
#define HD 512
#define NL 6

typedef __hip_bfloat16 bf16;
using short8 = __attribute__((ext_vector_type(8))) short;
using f32x4 = __attribute__((ext_vector_type(4))) float;

// async 16B/lane global->LDS: lds dest = lp + lane*16 (wave-uniform lp!)
#define ASYNC16(gp, lp)                                              \
    __builtin_amdgcn_global_load_lds(                                \
        (const __attribute__((address_space(1))) void*)(gp),         \
        (__attribute__((address_space(3))) void*)(lp), 16, 0, 0)

__device__ __forceinline__ float sigmoidf_(float x) { return 1.0f / (1.0f + expf(-x)); }
__device__ __forceinline__ float b2f(unsigned short u) {
    return __uint_as_float(((unsigned int)u) << 16);
}
__device__ __forceinline__ unsigned short f2b(float f) {
    bf16 b = __float2bfloat16(f);
    return *(unsigned short*)&b;
}

// ---------------- encoder ---------------------------------------------------------
__global__ __launch_bounds__(256) void enc_kernel(const float* __restrict__ x,
                                                  const float* __restrict__ w,
                                                  const float* __restrict__ b,
                                                  bf16* __restrict__ h) {
    __shared__ float xs[DIN];
    int row = blockIdx.x;
    int tid = threadIdx.x;
    if (tid < DIN) xs[tid] = x[row * DIN + tid];
    __syncthreads();
    for (int c = tid; c < HD; c += 256) {
        float acc = b[c];
#pragma unroll
        for (int k = 0; k < DIN; k++) acc = fmaf(xs[k], w[k * HD + c], acc);
        h[(size_t)row * HD + c] = __float2bfloat16(acc);
    }
}

// ---------------- weight transpose + hi/lo split ----------------------------------
__global__ __launch_bounds__(256) void twcvt_kernel(const float* __restrict__ W,
                                                    bf16* __restrict__ WtH,
                                                    bf16* __restrict__ WtL, int Nc) {
    __shared__ float s[32][33];
    int l = blockIdx.z;
    const float* Wp = W + (size_t)l * HD * Nc;
    size_t ob = (size_t)l * HD * Nc;
    int k0 = blockIdx.y * 32, c0 = blockIdx.x * 32;
    int tx = threadIdx.x & 31, ty = threadIdx.x >> 5;
    for (int r = ty; r < 32; r += 8) s[r][tx] = Wp[(size_t)(k0 + r) * Nc + c0 + tx];
    __syncthreads();
    for (int r = ty; r < 32; r += 8) {
        float v = s[tx][r];
        unsigned short hu = f2b(v);
        float hf = b2f(hu);
        size_t o = ob + (size_t)(c0 + r) * HD + k0 + tx;
        *(unsigned short*)&WtH[o] = hu;
        WtL[o] = __float2bfloat16(v - hf);
    }
}

// ---------------- bf16 MFMA GEMM (hi/lo weights), async staging -------------------
// tile 128x64, 4 waves x 32 rows; LDS 16 KB; swizzled seg layout.
template <bool RELU>
__global__ __launch_bounds__(256) void gemm_mfma(const bf16* __restrict__ A,
                                                 const bf16* __restrict__ WtH,
                                                 const bf16* __restrict__ WtL,
                                                 const float* __restrict__ bias,
                                                 bf16* __restrict__ C, int n) {
    __shared__ bf16 As[128 * 32];
    __shared__ bf16 BH[64 * 32];
    __shared__ bf16 BL[64 * 32];
    int tid = threadIdx.x;
    int wv = tid >> 6, lane = tid & 63;
    int quad = lane >> 4, l16 = lane & 15;
    int crow = lane >> 2, cseg = lane & 3;
    int gseg = cseg ^ (crow & 3);                 // swizzled global seg
    int fsw = (quad ^ (l16 & 3)) * 8;             // swizzled fragment offset (elems)
    int row0 = blockIdx.y * 128, col0 = blockIdx.x * 64;
    f32x4 acc[2][4] = {};

    // per-lane staging offsets (constant over K)
    int aoff[4];
    int alds[4];
    const bf16* wb = (wv == 2) ? WtH : WtL;
    bf16* bl_base = (wv == 2) ? BH : BL;
    int boff[4];
    if (wv < 2) {
#pragma unroll
        for (int j = 0; j < 4; j++) {
            int ch = wv * 4 + j;                  // 0..7
            int gr = row0 + ch * 16 + crow;
            if (gr > n - 1) gr = n - 1;           // clamp (dead rows guarded at write)
            aoff[j] = gr * HD + gseg * 8;
            alds[j] = ch * 512;                   // 16 rows * 32 elems
        }
    } else {
#pragma unroll
        for (int s = 0; s < 4; s++) boff[s] = (col0 + s * 16 + crow) * HD + gseg * 8;
    }

    for (int kt = 0; kt < 512; kt += 32) {
        if (wv < 2) {
#pragma unroll
            for (int j = 0; j < 4; j++) ASYNC16(&A[aoff[j] + kt], &As[alds[j]]);
        } else {
#pragma unroll
            for (int s = 0; s < 4; s++) ASYNC16(&wb[boff[s] + kt], &bl_base[s * 512]);
        }
        __syncthreads();
        short8 af[2];
#pragma unroll
        for (int i = 0; i < 2; i++)
            af[i] = *(const short8*)&As[(wv * 32 + i * 16 + l16) * 32 + fsw];
#pragma unroll
        for (int t = 0; t < 4; t++) {
            int fo = (t * 16 + l16) * 32 + fsw;
            short8 bh = *(const short8*)&BH[fo];
            short8 bl = *(const short8*)&BL[fo];
#pragma unroll
            for (int i = 0; i < 2; i++) {
                acc[i][t] = __builtin_amdgcn_mfma_f32_16x16x32_bf16(af[i], bh, acc[i][t], 0, 0, 0);
                acc[i][t] = __builtin_amdgcn_mfma_f32_16x16x32_bf16(af[i], bl, acc[i][t], 0, 0, 0);
            }
        }
        __syncthreads();
    }
#pragma unroll
    for (int t = 0; t < 4; t++) {
        int col = col0 + t * 16 + l16;
        float bb = bias[col];
#pragma unroll
        for (int i = 0; i < 2; i++) {
#pragma unroll
            for (int r = 0; r < 4; r++) {
                int row = row0 + wv * 32 + i * 16 + quad * 4 + r;
                if (row < n) {
                    float v = acc[i][t][r] + bb;
                    if (RELU) v = fmaxf(v, 0.0f);
                    C[(size_t)row * HD + col] = __float2bfloat16(v);
                }
            }
        }
    }
}

// ---------------- fused GRU (MFMA, hi/lo, rz-concat accumulators) -----------------
// tile 128 rows x 64 cols, 4 waves x 32 rows; LDS 64 KB (2 blocks/CU).
// acc sets: aR = gi_r+gh_r, aZ = gi_z+gh_z, aI = gi_n, aHn = gh_n.
// Ws planes: 0..5 Wi {r,z,n}x{hi,lo}; 6..11 Wh same.
__global__ __launch_bounds__(256, 2) void gru_mfma(const bf16* __restrict__ M,
                                                   const bf16* __restrict__ Hc,
                                                   const bf16* __restrict__ WiH,
                                                   const bf16* __restrict__ WiL,
                                                   const bf16* __restrict__ WhH,
                                                   const bf16* __restrict__ WhL,
                                                   const float* __restrict__ bih,
                                                   const float* __restrict__ bhh,
                                                   bf16* __restrict__ Hn, int n) {
    __shared__ bf16 Ms[128 * 32];
    __shared__ bf16 Hs[128 * 32];
    __shared__ bf16 Ws[12 * 64 * 32];
    int tid = threadIdx.x;
    int wv = tid >> 6, lane = tid & 63;
    int quad = lane >> 4, l16 = lane & 15;
    int crow = lane >> 2, cseg = lane & 3;
    int gseg = cseg ^ (crow & 3);
    int fsw = (quad ^ (l16 & 3)) * 8;
    int row0 = blockIdx.y * 128, col0 = blockIdx.x * 64;
    f32x4 aR[2][4] = {}, aZ[2][4] = {}, aI[2][4] = {}, aHn[2][4] = {};

    // staging precompute
    int moff[8];            // wave 0: M/H row chunks
    const bf16* wgp[4];     // waves 1-3: 4 weight planes each (per-lane ptr)
    int wlds[4];
    if (wv == 0) {
#pragma unroll
        for (int j = 0; j < 8; j++) {
            int gr = row0 + j * 16 + crow;
            if (gr > n - 1) gr = n - 1;
            moff[j] = gr * HD + gseg * 8;
        }
    } else {
        const bf16* wbase[4] = {WiH, WiL, WhH, WhL};
#pragma unroll
        for (int pp = 0; pp < 4; pp++) {
            int p = (wv - 1) * 4 + pp;            // 0..11
            int mat = (p >= 6);
            int q = p - mat * 6;
            int g = q >> 1, pl = q & 1;
            const bf16* base = wbase[mat * 2 + pl] + (size_t)(g * HD + col0) * HD;
            wgp[pp] = base + crow * HD + gseg * 8;
            wlds[pp] = p * 2048;                  // plane = 64*32 elems
        }
    }

    for (int kt = 0; kt < 512; kt += 32) {
        if (wv == 0) {
#pragma unroll
            for (int j = 0; j < 8; j++) {
                ASYNC16(&M[moff[j] + kt], &Ms[j * 512]);
                ASYNC16(&Hc[moff[j] + kt], &Hs[j * 512]);
            }
        } else {
#pragma unroll
            for (int pp = 0; pp < 4; pp++)
#pragma unroll
                for (int s = 0; s < 4; s++)
                    ASYNC16(wgp[pp] + (size_t)s * 16 * HD + kt, &Ws[wlds[pp] + s * 512]);
        }
        __syncthreads();
        short8 am[2], ah[2];
#pragma unroll
        for (int i = 0; i < 2; i++) {
            am[i] = *(const short8*)&Ms[(wv * 32 + i * 16 + l16) * 32 + fsw];
            ah[i] = *(const short8*)&Hs[(wv * 32 + i * 16 + l16) * 32 + fsw];
        }
#pragma unroll
        for (int t = 0; t < 4; t++) {
            int fo = (t * 16 + l16) * 32 + fsw;
            short8 wrh = *(const short8*)&Ws[0 * 2048 + fo];
            short8 wrl = *(const short8*)&Ws[1 * 2048 + fo];
            short8 wzh = *(const short8*)&Ws[2 * 2048 + fo];
            short8 wzl = *(const short8*)&Ws[3 * 2048 + fo];
            short8 wnh = *(const short8*)&Ws[4 * 2048 + fo];
            short8 wnl = *(const short8*)&Ws[5 * 2048 + fo];
            short8 vrh = *(const short8*)&Ws[6 * 2048 + fo];
            short8 vrl = *(const short8*)&Ws[7 * 2048 + fo];
            short8 vzh = *(const short8*)&Ws[8 * 2048 + fo];
            short8 vzl = *(const short8*)&Ws[9 * 2048 + fo];
            short8 vnh = *(const short8*)&Ws[10 * 2048 + fo];
            short8 vnl = *(const short8*)&Ws[11 * 2048 + fo];
#pragma unroll
            for (int i = 0; i < 2; i++) {
                aR[i][t] = __builtin_amdgcn_mfma_f32_16x16x32_bf16(am[i], wrh, aR[i][t], 0, 0, 0);
                aR[i][t] = __builtin_amdgcn_mfma_f32_16x16x32_bf16(am[i], wrl, aR[i][t], 0, 0, 0);
                aR[i][t] = __builtin_amdgcn_mfma_f32_16x16x32_bf16(ah[i], vrh, aR[i][t], 0, 0, 0);
                aR[i][t] = __builtin_amdgcn_mfma_f32_16x16x32_bf16(ah[i], vrl, aR[i][t], 0, 0, 0);
                aZ[i][t] = __builtin_amdgcn_mfma_f32_16x16x32_bf16(am[i], wzh, aZ[i][t], 0, 0, 0);
                aZ[i][t] = __builtin_amdgcn_mfma_f32_16x16x32_bf16(am[i], wzl, aZ[i][t], 0, 0, 0);
                aZ[i][t] = __builtin_amdgcn_mfma_f32_16x16x32_bf16(ah[i], vzh, aZ[i][t], 0, 0, 0);
                aZ[i][t] = __builtin_amdgcn_mfma_f32_16x16x32_bf16(ah[i], vzl, aZ[i][t], 0, 0, 0);
                aI[i][t] = __builtin_amdgcn_mfma_f32_16x16x32_bf16(am[i], wnh, aI[i][t], 0, 0, 0);
                aI[i][t] = __builtin_amdgcn_mfma_f32_16x16x32_bf16(am[i], wnl, aI[i][t], 0, 0, 0);
                aHn[i][t] = __builtin_amdgcn_mfma_f32_16x16x32_bf16(ah[i], vnh, aHn[i][t], 0, 0, 0);
                aHn[i][t] = __builtin_amdgcn_mfma_f32_16x16x32_bf16(ah[i], vnl, aHn[i][t], 0, 0, 0);
            }
        }
        __syncthreads();
    }
    const unsigned short* hp = (const unsigned short*)Hc;
#pragma unroll
    for (int t = 0; t < 4; t++) {
        int col = col0 + t * 16 + l16;
        float brz = bih[col] + bhh[col];
        float bzz = bih[HD + col] + bhh[HD + col];
        float bin_ = bih[2 * HD + col];
        float bhn_ = bhh[2 * HD + col];
#pragma unroll
        for (int i = 0; i < 2; i++) {
#pragma unroll
            for (int r = 0; r < 4; r++) {
                int row = row0 + wv * 32 + i * 16 + quad * 4 + r;
                if (row < n) {
                    float rg = sigmoidf_(aR[i][t][r] + brz);
                    float zg = sigmoidf_(aZ[i][t][r] + bzz);
                    float ng = tanhf(aI[i][t][r] + bin_ + rg * (aHn[i][t][r] + bhn_));
                    float hold = b2f(hp[(size_t)row * HD + col]);
                    Hn[(size_t)row * HD + col] = __float2bfloat16((1.0f - zg) * ng + zg * hold);
                }
            }
        }
    }
}

// ---------------- CSR build -------------------------------------------------------
__global__ __launch_bounds__(256) void deg_kernel(const int* __restrict__ dst,
                                                  int* __restrict__ deg) {
    int e = blockIdx.x * 256 + threadIdx.x;
    if (e < N_EDGES) atomicAdd(&deg[dst[e]], 1);
}

__global__ __launch_bounds__(1024) void scan_kernel(const int* __restrict__ deg,
                                                    int* __restrict__ offs) {
    __shared__ int buf[1024];
    __shared__ int carry_s;
    int tid = threadIdx.x;
    if (tid == 0) carry_s = 0;
    __syncthreads();
    for (int base = 0; base < N_NODES; base += 1024) {
        int v = (base + tid < N_NODES) ? deg[base + tid] : 0;
        buf[tid] = v;
        __syncthreads();
        for (int s = 1; s < 1024; s <<= 1) {
            int t = (tid >= s) ? buf[tid - s] : 0;
            __syncthreads();
            buf[tid] += t;
            __syncthreads();
        }
        int incl = buf[tid];
        if (base + tid < N_NODES) offs[base + tid] = carry_s + incl - v;
        __syncthreads();
        if (tid == 0) carry_s += buf[1023];
        __syncthreads();
    }
    if (tid == 0) offs[N_NODES] = carry_s;
}

__global__ __launch_bounds__(256) void bucket_kernel(const int* __restrict__ src,
                                                     const int* __restrict__ dst,
                                                     const int* __restrict__ offs,
                                                     int* __restrict__ cursor,
                                                     unsigned short* __restrict__ elist) {
    int e = blockIdx.x * 256 + threadIdx.x;
    if (e >= N_EDGES) return;
    int d = dst[e];
    int pos = atomicAdd(&cursor[d], 1);
    elist[offs[d] + pos] = (unsigned short)src[e];
}

// ---------------- gather-sum ------------------------------------------------------
__global__ __launch_bounds__(256) void gather_kernel(const bf16* __restrict__ msg,
                                                     bf16* __restrict__ m,
                                                     const unsigned short* __restrict__ elist,
                                                     const int* __restrict__ offs) {
    int nid = blockIdx.x, tid = threadIdx.x;
    int beg = offs[nid], end = offs[nid + 1];
    const unsigned int* mp = (const unsigned int*)msg;
    unsigned int u = mp[(size_t)nid * 256 + tid];
    float ax = b2f((unsigned short)(u & 0xffffu));
    float ay = b2f((unsigned short)(u >> 16));
    int e = beg;
    for (; e + 1 < end; e += 2) {
        unsigned int v0 = mp[(size_t)elist[e] * 256 + tid];
        unsigned int v1 = mp[(size_t)elist[e + 1] * 256 + tid];
        ax += b2f((unsigned short)(v0 & 0xffffu)) + b2f((unsigned short)(v1 & 0xffffu));
        ay += b2f((unsigned short)(v0 >> 16)) + b2f((unsigned short)(v1 >> 16));
    }
    if (e < end) {
        unsigned int v0 = mp[(size_t)elist[e] * 256 + tid];
        ax += b2f((unsigned short)(v0 & 0xffffu));
        ay += b2f((unsigned short)(v0 >> 16));
    }
    unsigned int out = ((unsigned int)f2b(ay) << 16) | (unsigned int)f2b(ax);
    ((unsigned int*)m)[(size_t)nid * 256 + tid] = out;
}

// ---------------- pooling + head --------------------------------------------------
__global__ __launch_bounds__(256) void pool_kernel(const bf16* __restrict__ h,
                                                   const int* __restrict__ batch,
                                                   float* __restrict__ pooled,
                                                   float* __restrict__ cnt) {
    int nrow = blockIdx.x, tid = threadIdx.x;
    int b = batch[nrow];
    const unsigned short* hp = (const unsigned short*)h;
    for (int c = tid; c < HD; c += 256)
        atomicAdd(&pooled[b * HD + c], b2f(hp[(size_t)nrow * HD + c]));
    if (tid == 0) atomicAdd(&cnt[b], 1.0f);
}

__global__ __launch_bounds__(256) void head_kernel(const float* __restrict__ pooled,
                                                   const float* __restrict__ cnt,
                                                   const float* __restrict__ w1,
                                                   const float* __restrict__ b1,
                                                   const float* __restrict__ w2,
                                                   const float* __restrict__ b2,
                                                   float* __restrict__ out) {
    __shared__ float prow[HD];
    __shared__ float red[256];
    int g = blockIdx.x, tid = threadIdx.x;
    float c = fmaxf(cnt[g], 1.0f);
    for (int j = tid; j < HD; j += 256) prow[j] = pooled[g * HD + j] / c;
    __syncthreads();
    float acc = b1[tid];
    for (int k = 0; k < HD; k++) acc = fmaf(prow[k], w1[k * 256 + tid], acc);
    red[tid] = fmaxf(acc, 0.0f) * w2[tid];
    __syncthreads();
    for (int s = 128; s > 0; s >>= 1) {
        if (tid < s) red[tid] += red[tid + s];
        __syncthreads();
    }
    if (tid == 0) out[g] = red[0] + b2[0];
}

// ---------------- launch ----------------------------------------------------------
extern "C" void kernel_launch(void* const* d_in, const int* in_sizes, int n_in,
                              void* d_out, int out_size, void* d_ws, size_t ws_size,
                              hipStream_t stream) {
    const float* x = (const float*)d_in[0];
    const int* eidx = (const int*)d_in[1];
    const int* batch = (const int*)d_in[2];
    const float* enc_w = (const float*)d_in[3];
    const float* enc_b = (const float*)d_in[4];
    const float* mlp_w1 = (const float*)d_in[5];
    const float* mlp_b1 = (const float*)d_in[6];
    const float* mlp_w2 = (const float*)d_in[7];
    const float* mlp_b2 = (const float*)d_in[8];
    const float* gru_wih = (const float*)d_in[9];
    const float* gru_whh = (const float*)d_in[10];
    const float* gru_bih = (const float*)d_in[11];
    const float* gru_bhh = (const float*)d_in[12];
    const float* head_w1 = (const float*)d_in[13];
    const float* head_b1 = (const float*)d_in[14];
    const float* head_w2 = (const float*)d_in[15];
    const float* head_b2 = (const float*)d_in[16];
    const int* src = eidx;
    const int* dst = eidx + N_EDGES;

    const size_t NH = (size_t)N_NODES * HD;
    char* p = (char*)d_ws;
    auto alloc = [&](size_t bytes) { char* q = p; p += (bytes + 255) & ~(size_t)255; return q; };
    bf16* S0 = (bf16*)alloc(NH * 2);
    bf16* S1 = (bf16*)alloc(NH * 2);
    bf16* S2 = (bf16*)alloc(NH * 2);
    bf16* w1tH = (bf16*)alloc((size_t)NL * HD * HD * 2);
    bf16* w1tL = (bf16*)alloc((size_t)NL * HD * HD * 2);
    bf16* w2tH = (bf16*)alloc((size_t)NL * HD * HD * 2);
    bf16* w2tL = (bf16*)alloc((size_t)NL * HD * HD * 2);
    bf16* wihtH = (bf16*)alloc((size_t)NL * 3 * HD * HD * 2);
    bf16* wihtL = (bf16*)alloc((size_t)NL * 3 * HD * HD * 2);
    bf16* whhtH = (bf16*)alloc((size_t)NL * 3 * HD * HD * 2);
    bf16* whhtL = (bf16*)alloc((size_t)NL * 3 * HD * HD * 2);
    float* pooled = (float*)alloc((size_t)N_GRAPH * HD * 4);
    float* cnt = (float*)alloc(N_GRAPH * 4);
    int* deg = (int*)alloc((N_NODES + 1) * 4);  // also cursor
    int* offs = (int*)alloc((N_NODES + 1) * 4);
    unsigned short* elist = (unsigned short*)alloc((size_t)N_EDGES * 2);
    // total ~144 MB (proven-safe envelope)

    twcvt_kernel<<<dim3(16, 16, NL), 256, 0, stream>>>(mlp_w1, w1tH, w1tL, HD);
    twcvt_kernel<<<dim3(16, 16, NL), 256, 0, stream>>>(mlp_w2, w2tH, w2tL, HD);
    twcvt_kernel<<<dim3(48, 16, NL), 256, 0, stream>>>(gru_wih, wihtH, wihtL, 3 * HD);
    twcvt_kernel<<<dim3(48, 16, NL), 256, 0, stream>>>(gru_whh, whhtH, whhtL, 3 * HD);

    hipMemsetAsync(deg, 0, (N_NODES + 1) * sizeof(int), stream);
    deg_kernel<<<(N_EDGES + 255) / 256, 256, 0, stream>>>(dst, deg);
    scan_kernel<<<1, 1024, 0, stream>>>(deg, offs);
    hipMemsetAsync(deg, 0, (N_NODES + 1) * sizeof(int), stream);
    bucket_kernel<<<(N_EDGES + 255) / 256, 256, 0, stream>>>(src, dst, offs, deg, elist);

    enc_kernel<<<N_NODES, 256, 0, stream>>>(x, enc_w, enc_b, S0);

    bf16* hcur = S0;
    bf16* hoth = S1;
    dim3 ggrid(8, (N_NODES + 127) / 128);
    dim3 ugrid(8, (N_NODES + 127) / 128);

    for (int l = 0; l < NL; l++) {
        size_t wsq = (size_t)l * HD * HD;
        size_t wgq = (size_t)l * 3 * HD * HD;
        const float* b1 = mlp_b1 + (size_t)l * HD;
        const float* b2 = mlp_b2 + (size_t)l * HD;
        const float* bih = gru_bih + (size_t)l * 3 * HD;
        const float* bhh = gru_bhh + (size_t)l * 3 * HD;

        gemm_mfma<true><<<ggrid, 256, 0, stream>>>(hcur, w1tH + wsq, w1tL + wsq, b1, hoth, N_NODES);
        gemm_mfma<false><<<ggrid, 256, 0, stream>>>(hoth, w2tH + wsq, w2tL + wsq, b2, S2, N_NODES);
        gather_kernel<<<N_NODES, 256, 0, stream>>>(S2, hoth, elist, offs);
        gru_mfma<<<ugrid, 256, 0, stream>>>(hoth, hcur, wihtH + wgq, wihtL + wgq,
                                            whhtH + wgq, whhtL + wgq, bih, bhh, S2, N_NODES);
        bf16* newh = S2;
        S2 = hcur;
        hcur = newh;
    }

    hipMemsetAsync(pooled, 0, ((size_t)N_GRAPH * HD + N_GRAPH) * sizeof(float), stream);
    pool_kernel<<<N_NODES, 256, 0, stream>>>(hcur, batch, pooled, cnt);
    head_kernel<<<N_GRAPH, 256, 0, stream>>>(pooled, cnt, head_w1, head_b1, head_w2, head_b2,
                                             (float*)d_out);
}

// Round 6
// 2823.056 us; speedup vs baseline: 18.0871x; 1.1418x over previous
//
#include <hip/hip_runtime.h>
#include <hip/hip_bf16.h>
#include <math.h>

#define N_NODES 30000
#define N_EDGES 480000
#define N_GRAPH 64
#define DIN 24
#define HD 512
#define NL 6

typedef __hip_bfloat16 bf16;
using short8 = __attribute__((ext_vector_type(8))) short;
using f32x4 = __attribute__((ext_vector_type(4))) float;

// async 16B/lane global->LDS: lds dest = lp + lane*16 (wave-uniform lp!)
#define ASYNC16(gp, lp)                                              \
    __builtin_amdgcn_global_load_lds(                                \
        (const __attribute__((address_space(1))) void*)(gp),         \
        (__attribute__((address_space(3))) void*)(lp), 16, 0, 0)

__device__ __forceinline__ float sigmoidf_(float x) { return 1.0f / (1.0f + expf(-x)); }
__device__ __forceinline__ float b2f(unsigned short u) {
    return __uint_as_float(((unsigned int)u) << 16);
}
__device__ __forceinline__ unsigned short f2b(float f) {
    bf16 b = __float2bfloat16(f);
    return *(unsigned short*)&b;
}

// ---------------- encoder ---------------------------------------------------------
__global__ __launch_bounds__(256) void enc_kernel(const float* __restrict__ x,
                                                  const float* __restrict__ w,
                                                  const float* __restrict__ b,
                                                  bf16* __restrict__ h) {
    __shared__ float xs[DIN];
    int row = blockIdx.x;
    int tid = threadIdx.x;
    if (tid < DIN) xs[tid] = x[row * DIN + tid];
    __syncthreads();
    for (int c = tid; c < HD; c += 256) {
        float acc = b[c];
#pragma unroll
        for (int k = 0; k < DIN; k++) acc = fmaf(xs[k], w[k * HD + c], acc);
        h[(size_t)row * HD + c] = __float2bfloat16(acc);
    }
}

// ---------------- weight transpose + hi/lo split ----------------------------------
__global__ __launch_bounds__(256) void twcvt_kernel(const float* __restrict__ W,
                                                    bf16* __restrict__ WtH,
                                                    bf16* __restrict__ WtL, int Nc) {
    __shared__ float s[32][33];
    int l = blockIdx.z;
    const float* Wp = W + (size_t)l * HD * Nc;
    size_t ob = (size_t)l * HD * Nc;
    int k0 = blockIdx.y * 32, c0 = blockIdx.x * 32;
    int tx = threadIdx.x & 31, ty = threadIdx.x >> 5;
    for (int r = ty; r < 32; r += 8) s[r][tx] = Wp[(size_t)(k0 + r) * Nc + c0 + tx];
    __syncthreads();
    for (int r = ty; r < 32; r += 8) {
        float v = s[tx][r];
        unsigned short hu = f2b(v);
        float hf = b2f(hu);
        size_t o = ob + (size_t)(c0 + r) * HD + k0 + tx;
        *(unsigned short*)&WtH[o] = hu;
        WtL[o] = __float2bfloat16(v - hf);
    }
}

// ---------------- bf16 MFMA GEMM (hi/lo weights): tile 128x128 --------------------
// 4 waves x 32 rows x 128 cols; LDS 24 KB; 2-way-free seg swizzle.
template <bool RELU>
__global__ __launch_bounds__(256) void gemm_mfma(const bf16* __restrict__ A,
                                                 const bf16* __restrict__ WtH,
                                                 const bf16* __restrict__ WtL,
                                                 const float* __restrict__ bias,
                                                 bf16* __restrict__ C, int n) {
    __shared__ bf16 As[128 * 32];
    __shared__ bf16 BH[128 * 32];
    __shared__ bf16 BL[128 * 32];
    int tid = threadIdx.x;
    int wv = tid >> 6, lane = tid & 63;
    int quad = lane >> 4, l16 = lane & 15;
    int crow = lane >> 2, cseg = lane & 3;
    int gseg = cseg ^ ((crow >> 1) & 3);          // 2-way-free swizzle
    int fsw = (quad ^ ((l16 >> 1) & 3)) * 8;
    int row0 = blockIdx.y * 128, col0 = blockIdx.x * 128;
    f32x4 acc[2][8] = {};

    int aoff[4], alds[4];
    int boff[8];
    const bf16* wb = (wv == 2) ? WtH : WtL;
    bf16* bdst = (wv == 2) ? BH : BL;
    if (wv < 2) {
#pragma unroll
        for (int j = 0; j < 4; j++) {
            int ch = wv * 4 + j;                  // 0..7 row chunk
            int gr = row0 + ch * 16 + crow;
            if (gr > n - 1) gr = n - 1;           // clamp; dead rows guarded at write
            aoff[j] = gr * HD + gseg * 8;
            alds[j] = ch * 512;
        }
    } else {
#pragma unroll
        for (int s = 0; s < 8; s++) boff[s] = (col0 + s * 16 + crow) * HD + gseg * 8;
    }

    for (int kt = 0; kt < 512; kt += 32) {
        if (wv < 2) {
#pragma unroll
            for (int j = 0; j < 4; j++) ASYNC16(&A[aoff[j] + kt], &As[alds[j]]);
        } else {
#pragma unroll
            for (int s = 0; s < 8; s++) ASYNC16(&wb[boff[s] + kt], &bdst[s * 512]);
        }
        __syncthreads();
        short8 af[2];
#pragma unroll
        for (int i = 0; i < 2; i++)
            af[i] = *(const short8*)&As[(wv * 32 + i * 16 + l16) * 32 + fsw];
#pragma unroll
        for (int t = 0; t < 8; t++) {
            int fo = (t * 16 + l16) * 32 + fsw;
            short8 bh = *(const short8*)&BH[fo];
            short8 bl = *(const short8*)&BL[fo];
#pragma unroll
            for (int i = 0; i < 2; i++) {
                acc[i][t] = __builtin_amdgcn_mfma_f32_16x16x32_bf16(af[i], bh, acc[i][t], 0, 0, 0);
                acc[i][t] = __builtin_amdgcn_mfma_f32_16x16x32_bf16(af[i], bl, acc[i][t], 0, 0, 0);
            }
        }
        __syncthreads();
    }
#pragma unroll
    for (int t = 0; t < 8; t++) {
        int col = col0 + t * 16 + l16;
        float bb = bias[col];
#pragma unroll
        for (int i = 0; i < 2; i++) {
#pragma unroll
            for (int r = 0; r < 4; r++) {
                int row = row0 + wv * 32 + i * 16 + quad * 4 + r;
                if (row < n) {
                    float v = acc[i][t][r] + bb;
                    if (RELU) v = fmaxf(v, 0.0f);
                    C[(size_t)row * HD + col] = __float2bfloat16(v);
                }
            }
        }
    }
}

// ---------------- fused GRU (MFMA, hi/lo, rz-concat accumulators) -----------------
// tile 128 rows x 64 cols, 4 waves x 32 rows; LDS 64 KB (2 blocks/CU).
__global__ __launch_bounds__(256, 2) void gru_mfma(const bf16* __restrict__ M,
                                                   const bf16* __restrict__ Hc,
                                                   const bf16* __restrict__ WiH,
                                                   const bf16* __restrict__ WiL,
                                                   const bf16* __restrict__ WhH,
                                                   const bf16* __restrict__ WhL,
                                                   const float* __restrict__ bih,
                                                   const float* __restrict__ bhh,
                                                   bf16* __restrict__ Hn, int n) {
    __shared__ bf16 Ms[128 * 32];
    __shared__ bf16 Hs[128 * 32];
    __shared__ bf16 Ws[12 * 64 * 32];
    int tid = threadIdx.x;
    int wv = tid >> 6, lane = tid & 63;
    int quad = lane >> 4, l16 = lane & 15;
    int crow = lane >> 2, cseg = lane & 3;
    int gseg = cseg ^ ((crow >> 1) & 3);
    int fsw = (quad ^ ((l16 >> 1) & 3)) * 8;
    int row0 = blockIdx.y * 128, col0 = blockIdx.x * 64;
    f32x4 aR[2][4] = {}, aZ[2][4] = {}, aI[2][4] = {}, aHn[2][4] = {};

    int moff[8];
    const bf16* wgp[4];
    int wlds[4];
    if (wv == 0) {
#pragma unroll
        for (int j = 0; j < 8; j++) {
            int gr = row0 + j * 16 + crow;
            if (gr > n - 1) gr = n - 1;
            moff[j] = gr * HD + gseg * 8;
        }
    } else {
        const bf16* wbase[4] = {WiH, WiL, WhH, WhL};
#pragma unroll
        for (int pp = 0; pp < 4; pp++) {
            int p = (wv - 1) * 4 + pp;            // 0..11
            int mat = (p >= 6);
            int q = p - mat * 6;
            int g = q >> 1, pl = q & 1;
            const bf16* base = wbase[mat * 2 + pl] + (size_t)(g * HD + col0) * HD;
            wgp[pp] = base + crow * HD + gseg * 8;
            wlds[pp] = p * 2048;
        }
    }

    for (int kt = 0; kt < 512; kt += 32) {
        if (wv == 0) {
#pragma unroll
            for (int j = 0; j < 8; j++) {
                ASYNC16(&M[moff[j] + kt], &Ms[j * 512]);
                ASYNC16(&Hc[moff[j] + kt], &Hs[j * 512]);
            }
        } else {
#pragma unroll
            for (int pp = 0; pp < 4; pp++)
#pragma unroll
                for (int s = 0; s < 4; s++)
                    ASYNC16(wgp[pp] + (size_t)s * 16 * HD + kt, &Ws[wlds[pp] + s * 512]);
        }
        __syncthreads();
        short8 am[2], ah[2];
#pragma unroll
        for (int i = 0; i < 2; i++) {
            am[i] = *(const short8*)&Ms[(wv * 32 + i * 16 + l16) * 32 + fsw];
            ah[i] = *(const short8*)&Hs[(wv * 32 + i * 16 + l16) * 32 + fsw];
        }
#pragma unroll
        for (int t = 0; t < 4; t++) {
            int fo = (t * 16 + l16) * 32 + fsw;
            short8 wrh = *(const short8*)&Ws[0 * 2048 + fo];
            short8 wrl = *(const short8*)&Ws[1 * 2048 + fo];
            short8 wzh = *(const short8*)&Ws[2 * 2048 + fo];
            short8 wzl = *(const short8*)&Ws[3 * 2048 + fo];
            short8 wnh = *(const short8*)&Ws[4 * 2048 + fo];
            short8 wnl = *(const short8*)&Ws[5 * 2048 + fo];
            short8 vrh = *(const short8*)&Ws[6 * 2048 + fo];
            short8 vrl = *(const short8*)&Ws[7 * 2048 + fo];
            short8 vzh = *(const short8*)&Ws[8 * 2048 + fo];
            short8 vzl = *(const short8*)&Ws[9 * 2048 + fo];
            short8 vnh = *(const short8*)&Ws[10 * 2048 + fo];
            short8 vnl = *(const short8*)&Ws[11 * 2048 + fo];
#pragma unroll
            for (int i = 0; i < 2; i++) {
                aR[i][t] = __builtin_amdgcn_mfma_f32_16x16x32_bf16(am[i], wrh, aR[i][t], 0, 0, 0);
                aR[i][t] = __builtin_amdgcn_mfma_f32_16x16x32_bf16(am[i], wrl, aR[i][t], 0, 0, 0);
                aR[i][t] = __builtin_amdgcn_mfma_f32_16x16x32_bf16(ah[i], vrh, aR[i][t], 0, 0, 0);
                aR[i][t] = __builtin_amdgcn_mfma_f32_16x16x32_bf16(ah[i], vrl, aR[i][t], 0, 0, 0);
                aZ[i][t] = __builtin_amdgcn_mfma_f32_16x16x32_bf16(am[i], wzh, aZ[i][t], 0, 0, 0);
                aZ[i][t] = __builtin_amdgcn_mfma_f32_16x16x32_bf16(am[i], wzl, aZ[i][t], 0, 0, 0);
                aZ[i][t] = __builtin_amdgcn_mfma_f32_16x16x32_bf16(ah[i], vzh, aZ[i][t], 0, 0, 0);
                aZ[i][t] = __builtin_amdgcn_mfma_f32_16x16x32_bf16(ah[i], vzl, aZ[i][t], 0, 0, 0);
                aI[i][t] = __builtin_amdgcn_mfma_f32_16x16x32_bf16(am[i], wnh, aI[i][t], 0, 0, 0);
                aI[i][t] = __builtin_amdgcn_mfma_f32_16x16x32_bf16(am[i], wnl, aI[i][t], 0, 0, 0);
                aHn[i][t] = __builtin_amdgcn_mfma_f32_16x16x32_bf16(ah[i], vnh, aHn[i][t], 0, 0, 0);
                aHn[i][t] = __builtin_amdgcn_mfma_f32_16x16x32_bf16(ah[i], vnl, aHn[i][t], 0, 0, 0);
            }
        }
        __syncthreads();
    }
    const unsigned short* hp = (const unsigned short*)Hc;
#pragma unroll
    for (int t = 0; t < 4; t++) {
        int col = col0 + t * 16 + l16;
        float brz = bih[col] + bhh[col];
        float bzz = bih[HD + col] + bhh[HD + col];
        float bin_ = bih[2 * HD + col];
        float bhn_ = bhh[2 * HD + col];
#pragma unroll
        for (int i = 0; i < 2; i++) {
#pragma unroll
            for (int r = 0; r < 4; r++) {
                int row = row0 + wv * 32 + i * 16 + quad * 4 + r;
                if (row < n) {
                    float rg = sigmoidf_(aR[i][t][r] + brz);
                    float zg = sigmoidf_(aZ[i][t][r] + bzz);
                    float ng = tanhf(aI[i][t][r] + bin_ + rg * (aHn[i][t][r] + bhn_));
                    float hold = b2f(hp[(size_t)row * HD + col]);
                    Hn[(size_t)row * HD + col] = __float2bfloat16((1.0f - zg) * ng + zg * hold);
                }
            }
        }
    }
}

// ---------------- CSR build -------------------------------------------------------
__global__ __launch_bounds__(256) void deg_kernel(const int* __restrict__ dst,
                                                  int* __restrict__ deg) {
    int e = blockIdx.x * 256 + threadIdx.x;
    if (e < N_EDGES) atomicAdd(&deg[dst[e]], 1);
}

__global__ __launch_bounds__(1024) void scan_kernel(const int* __restrict__ deg,
                                                    int* __restrict__ offs) {
    __shared__ int buf[1024];
    __shared__ int carry_s;
    int tid = threadIdx.x;
    if (tid == 0) carry_s = 0;
    __syncthreads();
    for (int base = 0; base < N_NODES; base += 1024) {
        int v = (base + tid < N_NODES) ? deg[base + tid] : 0;
        buf[tid] = v;
        __syncthreads();
        for (int s = 1; s < 1024; s <<= 1) {
            int t = (tid >= s) ? buf[tid - s] : 0;
            __syncthreads();
            buf[tid] += t;
            __syncthreads();
        }
        int incl = buf[tid];
        if (base + tid < N_NODES) offs[base + tid] = carry_s + incl - v;
        __syncthreads();
        if (tid == 0) carry_s += buf[1023];
        __syncthreads();
    }
    if (tid == 0) offs[N_NODES] = carry_s;
}

__global__ __launch_bounds__(256) void bucket_kernel(const int* __restrict__ src,
                                                     const int* __restrict__ dst,
                                                     const int* __restrict__ offs,
                                                     int* __restrict__ cursor,
                                                     unsigned short* __restrict__ elist) {
    int e = blockIdx.x * 256 + threadIdx.x;
    if (e >= N_EDGES) return;
    int d = dst[e];
    int pos = atomicAdd(&cursor[d], 1);
    elist[offs[d] + pos] = (unsigned short)src[e];
}

// ---------------- gather-sum ------------------------------------------------------
__global__ __launch_bounds__(256) void gather_kernel(const bf16* __restrict__ msg,
                                                     bf16* __restrict__ m,
                                                     const unsigned short* __restrict__ elist,
                                                     const int* __restrict__ offs) {
    int nid = blockIdx.x, tid = threadIdx.x;
    int beg = offs[nid], end = offs[nid + 1];
    const unsigned int* mp = (const unsigned int*)msg;
    unsigned int u = mp[(size_t)nid * 256 + tid];
    float ax = b2f((unsigned short)(u & 0xffffu));
    float ay = b2f((unsigned short)(u >> 16));
    int e = beg;
    for (; e + 3 < end; e += 4) {
        unsigned int v0 = mp[(size_t)elist[e] * 256 + tid];
        unsigned int v1 = mp[(size_t)elist[e + 1] * 256 + tid];
        unsigned int v2 = mp[(size_t)elist[e + 2] * 256 + tid];
        unsigned int v3 = mp[(size_t)elist[e + 3] * 256 + tid];
        ax += b2f((unsigned short)(v0 & 0xffffu)) + b2f((unsigned short)(v1 & 0xffffu)) +
              b2f((unsigned short)(v2 & 0xffffu)) + b2f((unsigned short)(v3 & 0xffffu));
        ay += b2f((unsigned short)(v0 >> 16)) + b2f((unsigned short)(v1 >> 16)) +
              b2f((unsigned short)(v2 >> 16)) + b2f((unsigned short)(v3 >> 16));
    }
    for (; e < end; e++) {
        unsigned int v0 = mp[(size_t)elist[e] * 256 + tid];
        ax += b2f((unsigned short)(v0 & 0xffffu));
        ay += b2f((unsigned short)(v0 >> 16));
    }
    unsigned int out = ((unsigned int)f2b(ay) << 16) | (unsigned int)f2b(ax);
    ((unsigned int*)m)[(size_t)nid * 256 + tid] = out;
}

// ---------------- pooling (segmented, batch sorted -> no atomics) -----------------
__global__ __launch_bounds__(256) void pool_kernel(const bf16* __restrict__ h,
                                                   const int* __restrict__ batch,
                                                   float* __restrict__ pooled,
                                                   float* __restrict__ cnt) {
    int g = blockIdx.x;
    int col = blockIdx.y * 256 + threadIdx.x;
    // lower_bound for g and g+1 in sorted batch
    int lo = 0, hi = N_NODES;
    while (lo < hi) { int mid = (lo + hi) >> 1; if (batch[mid] < g) lo = mid + 1; else hi = mid; }
    int gs = lo;
    hi = N_NODES;
    while (lo < hi) { int mid = (lo + hi) >> 1; if (batch[mid] < g + 1) lo = mid + 1; else hi = mid; }
    int ge = lo;
    const unsigned short* hp = (const unsigned short*)h;
    float acc = 0.0f;
    int r = gs;
    for (; r + 3 < ge; r += 4) {
        acc += b2f(hp[(size_t)r * HD + col]) + b2f(hp[(size_t)(r + 1) * HD + col]) +
               b2f(hp[(size_t)(r + 2) * HD + col]) + b2f(hp[(size_t)(r + 3) * HD + col]);
    }
    for (; r < ge; r++) acc += b2f(hp[(size_t)r * HD + col]);
    pooled[g * HD + col] = acc;
    if (blockIdx.y == 0 && threadIdx.x == 0) cnt[g] = (float)(ge - gs);
}

__global__ __launch_bounds__(256) void head_kernel(const float* __restrict__ pooled,
                                                   const float* __restrict__ cnt,
                                                   const float* __restrict__ w1,
                                                   const float* __restrict__ b1,
                                                   const float* __restrict__ w2,
                                                   const float* __restrict__ b2,
                                                   float* __restrict__ out) {
    __shared__ float prow[HD];
    __shared__ float red[256];
    int g = blockIdx.x, tid = threadIdx.x;
    float c = fmaxf(cnt[g], 1.0f);
    for (int j = tid; j < HD; j += 256) prow[j] = pooled[g * HD + j] / c;
    __syncthreads();
    float acc = b1[tid];
    for (int k = 0; k < HD; k++) acc = fmaf(prow[k], w1[k * 256 + tid], acc);
    red[tid] = fmaxf(acc, 0.0f) * w2[tid];
    __syncthreads();
    for (int s = 128; s > 0; s >>= 1) {
        if (tid < s) red[tid] += red[tid + s];
        __syncthreads();
    }
    if (tid == 0) out[g] = red[0] + b2[0];
}

// ---------------- launch ----------------------------------------------------------
extern "C" void kernel_launch(void* const* d_in, const int* in_sizes, int n_in,
                              void* d_out, int out_size, void* d_ws, size_t ws_size,
                              hipStream_t stream) {
    const float* x = (const float*)d_in[0];
    const int* eidx = (const int*)d_in[1];
    const int* batch = (const int*)d_in[2];
    const float* enc_w = (const float*)d_in[3];
    const float* enc_b = (const float*)d_in[4];
    const float* mlp_w1 = (const float*)d_in[5];
    const float* mlp_b1 = (const float*)d_in[6];
    const float* mlp_w2 = (const float*)d_in[7];
    const float* mlp_b2 = (const float*)d_in[8];
    const float* gru_wih = (const float*)d_in[9];
    const float* gru_whh = (const float*)d_in[10];
    const float* gru_bih = (const float*)d_in[11];
    const float* gru_bhh = (const float*)d_in[12];
    const float* head_w1 = (const float*)d_in[13];
    const float* head_b1 = (const float*)d_in[14];
    const float* head_w2 = (const float*)d_in[15];
    const float* head_b2 = (const float*)d_in[16];
    const int* src = eidx;
    const int* dst = eidx + N_EDGES;

    const size_t NH = (size_t)N_NODES * HD;
    char* p = (char*)d_ws;
    auto alloc = [&](size_t bytes) { char* q = p; p += (bytes + 255) & ~(size_t)255; return q; };
    bf16* S0 = (bf16*)alloc(NH * 2);
    bf16* S1 = (bf16*)alloc(NH * 2);
    bf16* S2 = (bf16*)alloc(NH * 2);
    bf16* w1tH = (bf16*)alloc((size_t)NL * HD * HD * 2);
    bf16* w1tL = (bf16*)alloc((size_t)NL * HD * HD * 2);
    bf16* w2tH = (bf16*)alloc((size_t)NL * HD * HD * 2);
    bf16* w2tL = (bf16*)alloc((size_t)NL * HD * HD * 2);
    bf16* wihtH = (bf16*)alloc((size_t)NL * 3 * HD * HD * 2);
    bf16* wihtL = (bf16*)alloc((size_t)NL * 3 * HD * HD * 2);
    bf16* whhtH = (bf16*)alloc((size_t)NL * 3 * HD * HD * 2);
    bf16* whhtL = (bf16*)alloc((size_t)NL * 3 * HD * HD * 2);
    float* pooled = (float*)alloc((size_t)N_GRAPH * HD * 4);
    float* cnt = (float*)alloc(N_GRAPH * 4);
    int* deg = (int*)alloc((N_NODES + 1) * 4);  // also cursor
    int* offs = (int*)alloc((N_NODES + 1) * 4);
    unsigned short* elist = (unsigned short*)alloc((size_t)N_EDGES * 2);
    // total ~144 MB (proven-safe envelope)

    twcvt_kernel<<<dim3(16, 16, NL), 256, 0, stream>>>(mlp_w1, w1tH, w1tL, HD);
    twcvt_kernel<<<dim3(16, 16, NL), 256, 0, stream>>>(mlp_w2, w2tH, w2tL, HD);
    twcvt_kernel<<<dim3(48, 16, NL), 256, 0, stream>>>(gru_wih, wihtH, wihtL, 3 * HD);
    twcvt_kernel<<<dim3(48, 16, NL), 256, 0, stream>>>(gru_whh, whhtH, whhtL, 3 * HD);

    hipMemsetAsync(deg, 0, (N_NODES + 1) * sizeof(int), stream);
    deg_kernel<<<(N_EDGES + 255) / 256, 256, 0, stream>>>(dst, deg);
    scan_kernel<<<1, 1024, 0, stream>>>(deg, offs);
    hipMemsetAsync(deg, 0, (N_NODES + 1) * sizeof(int), stream);
    bucket_kernel<<<(N_EDGES + 255) / 256, 256, 0, stream>>>(src, dst, offs, deg, elist);

    enc_kernel<<<N_NODES, 256, 0, stream>>>(x, enc_w, enc_b, S0);

    bf16* hcur = S0;
    bf16* hoth = S1;
    dim3 ggrid(4, (N_NODES + 127) / 128);   // 128-col tiles
    dim3 ugrid(8, (N_NODES + 127) / 128);

    for (int l = 0; l < NL; l++) {
        size_t wsq = (size_t)l * HD * HD;
        size_t wgq = (size_t)l * 3 * HD * HD;
        const float* b1 = mlp_b1 + (size_t)l * HD;
        const float* b2 = mlp_b2 + (size_t)l * HD;
        const float* bih = gru_bih + (size_t)l * 3 * HD;
        const float* bhh = gru_bhh + (size_t)l * 3 * HD;

        gemm_mfma<true><<<ggrid, 256, 0, stream>>>(hcur, w1tH + wsq, w1tL + wsq, b1, hoth, N_NODES);
        gemm_mfma<false><<<ggrid, 256, 0, stream>>>(hoth, w2tH + wsq, w2tL + wsq, b2, S2, N_NODES);
        gather_kernel<<<N_NODES, 256, 0, stream>>>(S2, hoth, elist, offs);
        gru_mfma<<<ugrid, 256, 0, stream>>>(hoth, hcur, wihtH + wgq, wihtL + wgq,
                                            whhtH + wgq, whhtL + wgq, bih, bhh, S2, N_NODES);
        bf16* newh = S2;
        S2 = hcur;
        hcur = newh;
    }

    pool_kernel<<<dim3(N_GRAPH, 2), 256, 0, stream>>>(hcur, batch, pooled, cnt);
    head_kernel<<<N_GRAPH, 256, 0, stream>>>(pooled, cnt, head_w1, head_b1, head_w2, head_b2,
                                             (float*)d_out);
}